// Round 4
// baseline (872.797 us; speedup 1.0000x reference)
//
#include <hip/hip_runtime.h>
#include <hip/hip_bf16.h>

// Sparse graph-attention Gumbel mask.
//
// Restructuring: with M = Wq^T Wk [E,E],
//   w_ui[e] = adj*( Xu[r]·C[c] + t1[r] + u1[c] + c0 ),  C = Xi M^T
//   w_iu[e] = adj*( Xu[r]·D[c] + t2[r] + u2[c] + c0 ),  D = Xi M
// Per-edge gather = Xu[r] (512B) + CD[c] (1KB).
//
// R4: counting-sort edges by (rblk, c); contiguous per-group chunks over the
// whole sorted array; virtual-block remap keeps adjacent chunks on one XCD.
// exp/sum pass uses plain per-edge atomics (R2-proven pattern) on sorted data.

#define EMB 128
#define TAUINV 2.0f
#define NRB 8

__device__ __forceinline__ unsigned fkey(float f) {
    unsigned u = __float_as_uint(f);
    return (u & 0x80000000u) ? ~u : (u | 0x80000000u);
}
__device__ __forceinline__ float fdecode(unsigned u) {
    return __uint_as_float((u & 0x80000000u) ? (u ^ 0x80000000u) : ~u);
}

// ---- BIGM[k][j] (j<128: M[j][k]; j>=128: M[k][j-128]), v1, v2, c0
__global__ void k_prep(const float* __restrict__ Wq, const float* __restrict__ Wk,
                       const float* __restrict__ bq, const float* __restrict__ bk,
                       float* __restrict__ BIGM, float* __restrict__ v1,
                       float* __restrict__ v2, float* __restrict__ c0) {
    int e1 = blockIdx.x, e2 = threadIdx.x;
    float acc = 0.f;
    for (int a = 0; a < EMB; ++a) acc += Wq[a * EMB + e1] * Wk[a * EMB + e2];
    BIGM[e2 * 256 + e1] = acc;
    BIGM[e1 * 256 + 128 + e2] = acc;
    if (e2 == 0) { float s = 0.f; for (int a = 0; a < EMB; ++a) s += Wq[a * EMB + e1] * bk[a]; v1[e1] = s; }
    if (e2 == 1) { float s = 0.f; for (int a = 0; a < EMB; ++a) s += Wk[a * EMB + e1] * bq[a]; v2[e1] = s; }
    if (e1 == 0 && e2 == 2) { float s = 0.f; for (int a = 0; a < EMB; ++a) s += bq[a] * bk[a]; *c0 = s; }
}

// ---- CD[m][j] = sum_k Xi[m][k] * BIGM[k][j]
__global__ __launch_bounds__(256) void k_cd(const float* __restrict__ Xi,
                                            const float* __restrict__ BIGM,
                                            float* __restrict__ CD, int nItems) {
    __shared__ float Xs[32][EMB];
    __shared__ float Ms[32][256];
    const int t = threadIdx.x;
    const int m0 = blockIdx.x * 32;

    const float4* Xi4 = (const float4*)Xi;
    float4* Xs4 = (float4*)Xs;
    for (int idx = t; idx < 32 * 32; idx += 256) {
        int r = idx >> 5, c = idx & 31;
        int row = m0 + r;
        Xs4[idx] = (row < nItems) ? Xi4[(size_t)row * 32 + c]
                                  : make_float4(0.f, 0.f, 0.f, 0.f);
    }

    const int tc = t & 63;
    const int tr = t >> 6;
    float4 acc[8] = {};

    const float4* BG4 = (const float4*)BIGM;
    float4* Ms4 = (float4*)Ms;
    for (int kc = 0; kc < EMB; kc += 32) {
        __syncthreads();
        for (int idx = t; idx < 32 * 64; idx += 256)
            Ms4[idx] = BG4[(size_t)(kc + (idx >> 6)) * 64 + (idx & 63)];
        __syncthreads();
#pragma unroll
        for (int kk = 0; kk < 32; ++kk) {
            float4 w = Ms4[kk * 64 + tc];
#pragma unroll
            for (int i = 0; i < 8; ++i) {
                float x = Xs[tr * 8 + i][kc + kk];
                acc[i].x += x * w.x; acc[i].y += x * w.y;
                acc[i].z += x * w.z; acc[i].w += x * w.w;
            }
        }
    }
#pragma unroll
    for (int i = 0; i < 8; ++i) {
        int row = m0 + tr * 8 + i;
        if (row < nItems)
            ((float4*)(CD + (size_t)row * 256))[tc] = acc[i];
    }
}

// ---- o1[g] = X[g]·a, o2[g] = X[g]·b
__global__ void k_rowdot(const float* __restrict__ X, int n,
                         const float* __restrict__ a, const float* __restrict__ b,
                         float* __restrict__ o1, float* __restrict__ o2) {
    int g = blockIdx.x * 8 + (threadIdx.x >> 5);
    int l = threadIdx.x & 31;
    if (g >= n) return;
    float4 x = ((const float4*)(X + (size_t)g * EMB))[l];
    float4 av = ((const float4*)a)[l];
    float4 bv = ((const float4*)b)[l];
    float p1 = x.x * av.x + x.y * av.y + x.z * av.z + x.w * av.w;
    float p2 = x.x * bv.x + x.y * bv.y + x.z * bv.z + x.w * bv.w;
    for (int off = 16; off; off >>= 1) { p1 += __shfl_xor(p1, off); p2 += __shfl_xor(p2, off); }
    if (l == 0) { o1[g] = p1; o2[g] = p2; }
}

// ================= sort machinery =================
__global__ void k_hist(const int* __restrict__ rows, const int* __restrict__ cols,
                       int nnz, int U, int I, unsigned* __restrict__ cnt) {
    int i = blockIdx.x * blockDim.x + threadIdx.x, st = gridDim.x * blockDim.x;
    for (int e = i; e < nnz; e += st) {
        int rb = (int)(((long long)rows[e] * NRB) / U);
        atomicAdd(&cnt[rb * I + cols[e]], 1u);
    }
}

__global__ void k_scan1(const unsigned* __restrict__ cnt, unsigned* __restrict__ off,
                        unsigned* __restrict__ bsum, int n) {
    __shared__ unsigned sh[256];
    int i = blockIdx.x * 256 + threadIdx.x;
    unsigned v = (i < n) ? cnt[i] : 0u;
    sh[threadIdx.x] = v; __syncthreads();
    for (int d = 1; d < 256; d <<= 1) {
        unsigned t = (threadIdx.x >= d) ? sh[threadIdx.x - d] : 0u; __syncthreads();
        sh[threadIdx.x] += t; __syncthreads();
    }
    if (i < n) off[i] = sh[threadIdx.x] - v;
    if (threadIdx.x == 255) bsum[blockIdx.x] = sh[255];
}

__global__ void k_scan2(unsigned* __restrict__ bsum, int nb) {
    __shared__ unsigned sh[256];
    __shared__ unsigned carry;
    if (threadIdx.x == 0) carry = 0u;
    __syncthreads();
    for (int base = 0; base < nb; base += 256) {
        int i = base + threadIdx.x;
        unsigned v = (i < nb) ? bsum[i] : 0u;
        sh[threadIdx.x] = v; __syncthreads();
        for (int d = 1; d < 256; d <<= 1) {
            unsigned t = (threadIdx.x >= d) ? sh[threadIdx.x - d] : 0u; __syncthreads();
            sh[threadIdx.x] += t; __syncthreads();
        }
        unsigned c = carry;
        if (i < nb) bsum[i] = c + sh[threadIdx.x] - v;
        __syncthreads();
        if (threadIdx.x == 0) carry = c + sh[255];
        __syncthreads();
    }
}

__global__ void k_scan3(unsigned* __restrict__ off, const unsigned* __restrict__ bsum, int n) {
    int i = blockIdx.x * 256 + threadIdx.x;
    if (i < n) off[i] += bsum[blockIdx.x];
}

__global__ void k_scatter(const int* __restrict__ rows, const int* __restrict__ cols,
                          const float* __restrict__ adj, const float* __restrict__ gu1,
                          const float* __restrict__ gu2, int nnz, int U, int I,
                          unsigned* __restrict__ off, int* __restrict__ r_s,
                          int* __restrict__ c_s, float* __restrict__ a_s,
                          float* __restrict__ g1_s, float* __restrict__ g2_s,
                          int* __restrict__ iperm) {
    int i = blockIdx.x * blockDim.x + threadIdx.x, st = gridDim.x * blockDim.x;
    for (int e = i; e < nnz; e += st) {
        int r = rows[e], c = cols[e];
        int rb = (int)(((long long)r * NRB) / U);
        unsigned pos = atomicAdd(&off[rb * I + c], 1u);
        r_s[pos] = r; c_s[pos] = c;
        a_s[pos] = adj[e]; g1_s[pos] = gu1[e]; g2_s[pos] = gu2[e];
        iperm[e] = (int)pos;
    }
}

// ---- sorted edge kernel: contiguous chunk per 32-lane group over [0,nnz);
// virtual-block remap so virtually-adjacent chunks share an XCD.
__global__ __launch_bounds__(256) void k_edge3(
    const float* __restrict__ Xu, const float* __restrict__ CD,
    const float* __restrict__ t1, const float* __restrict__ t2,
    const float* __restrict__ u1, const float* __restrict__ u2,
    const float* __restrict__ c0p,
    const int* __restrict__ r_s, const int* __restrict__ c_s,
    const float* __restrict__ a_s, const float* __restrict__ g1_s,
    const float* __restrict__ g2_s, float* __restrict__ L1s, float* __restrict__ L2s,
    unsigned* __restrict__ mx1, unsigned* __restrict__ mx2, int nnz) {
    const unsigned vb = (blockIdx.x & 7) * (gridDim.x >> 3) + (blockIdx.x >> 3);
    const unsigned g = threadIdx.x >> 5, l = threadIdx.x & 31;
    const unsigned G = gridDim.x * 8;
    const unsigned widx = vb * 8 + g;
    const unsigned chunk = ((unsigned)nnz + G - 1) / G;
    unsigned j0 = widx * chunk;
    unsigned j1 = j0 + chunk; if (j1 > (unsigned)nnz) j1 = (unsigned)nnz;
    const float c0 = *c0p;
    for (unsigned j = j0; j < j1; ++j) {
        int r = r_s[j], c = c_s[j];
        float4 xu = ((const float4*)(Xu + (size_t)r * EMB))[l];
        const float4* cd = (const float4*)(CD + (size_t)c * 256);
        float4 cv = cd[l];
        float4 dv = cd[32 + l];
        float p1 = xu.x * cv.x + xu.y * cv.y + xu.z * cv.z + xu.w * cv.w;
        float p2 = xu.x * dv.x + xu.y * dv.y + xu.z * dv.z + xu.w * dv.w;
        for (int off = 16; off; off >>= 1) { p1 += __shfl_xor(p1, off); p2 += __shfl_xor(p2, off); }
        if (l < 2) {
            float p = (l == 0) ? p1 : p2;
            float tt = (l == 0) ? t1[r] : t2[r];
            float uu = (l == 0) ? u1[c] : u2[c];
            float gg = logf(-logf(((l == 0) ? g1_s : g2_s)[j]));
            float w = a_s[j] * (p + tt + uu + c0);
            float lg = (w - gg) * TAUINV;
            if (l == 0) { L1s[j] = lg; atomicMax(mx1 + r, fkey(lg)); }
            else        { L2s[j] = lg; atomicMax(mx2 + c, fkey(lg)); }
        }
    }
}

// ---- exp + segment sums, plain per-edge atomics (R2-proven pattern)
__global__ void k_exp2(const int* __restrict__ r_s, const int* __restrict__ c_s,
                       float* __restrict__ L1s, float* __restrict__ L2s,
                       const unsigned* __restrict__ mx1, const unsigned* __restrict__ mx2,
                       float* __restrict__ s1, float* __restrict__ s2, int nnz) {
    int i = blockIdx.x * blockDim.x + threadIdx.x, st = gridDim.x * blockDim.x;
    for (int j = i; j < nnz; j += st) {
        int r = r_s[j], c = c_s[j];
        float e1 = expf(L1s[j] - fdecode(mx1[r]));
        float e2 = expf(L2s[j] - fdecode(mx2[c]));
        L1s[j] = e1; L2s[j] = e2;
        atomicAdd(s1 + r, e1);
        atomicAdd(s2 + c, e2);
    }
}

// ---- un-permute + normalize
__global__ void k_out(const int* __restrict__ rows, const int* __restrict__ cols,
                      const int* __restrict__ iperm, const float* __restrict__ L1s,
                      const float* __restrict__ L2s, const float* __restrict__ s1,
                      const float* __restrict__ s2, float* __restrict__ out, int nnz) {
    int i = blockIdx.x * blockDim.x + threadIdx.x, st = gridDim.x * blockDim.x;
    for (int e = i; e < nnz; e += st) {
        int p = iperm[e];
        out[e] = L1s[p] / s1[rows[e]];
        out[nnz + e] = L2s[p] / s2[cols[e]];
    }
}

// ================= fallback (unsorted) path =================
__global__ __launch_bounds__(256) void k_edge1(
    const float* __restrict__ Xu, const float* __restrict__ CD,
    const float* __restrict__ t1, const float* __restrict__ t2,
    const float* __restrict__ u1, const float* __restrict__ u2,
    const float* __restrict__ c0p, const float* __restrict__ adj,
    const float* __restrict__ gu1, const float* __restrict__ gu2,
    const int* __restrict__ rows, const int* __restrict__ cols,
    float* __restrict__ L1, float* __restrict__ L2,
    unsigned* __restrict__ mx1, unsigned* __restrict__ mx2, int nnz) {
    const int gid = blockIdx.x * 8 + (threadIdx.x >> 5);
    const int l = threadIdx.x & 31;
    const int stride = gridDim.x * 8;
    const float c0 = *c0p;
    for (int e = gid; e < nnz; e += stride) {
        int r = rows[e], c = cols[e];
        float4 xu = ((const float4*)(Xu + (size_t)r * EMB))[l];
        const float4* cd = (const float4*)(CD + (size_t)c * 256);
        float4 cv = cd[l];
        float4 dv = cd[32 + l];
        float p1 = xu.x * cv.x + xu.y * cv.y + xu.z * cv.z + xu.w * cv.w;
        float p2 = xu.x * dv.x + xu.y * dv.y + xu.z * dv.z + xu.w * dv.w;
        for (int off = 16; off; off >>= 1) { p1 += __shfl_xor(p1, off); p2 += __shfl_xor(p2, off); }
        if (l < 2) {
            float p = (l == 0) ? p1 : p2;
            float tt = (l == 0) ? t1[r] : t2[r];
            float uu = (l == 0) ? u1[c] : u2[c];
            float g = logf(-logf(((l == 0) ? gu1 : gu2)[e]));
            float w = adj[e] * (p + tt + uu + c0);
            float lg = (w - g) * TAUINV;
            if (l == 0) { L1[e] = lg; atomicMax(mx1 + r, fkey(lg)); }
            else        { L2[e] = lg; atomicMax(mx2 + c, fkey(lg)); }
        }
    }
}

__global__ void k_exp(const float* __restrict__ L1, const float* __restrict__ L2,
                      const int* __restrict__ rows, const int* __restrict__ cols,
                      const unsigned* __restrict__ mx1, const unsigned* __restrict__ mx2,
                      float* __restrict__ s1, float* __restrict__ s2,
                      float* __restrict__ out, int nnz) {
    int i0 = blockIdx.x * blockDim.x + threadIdx.x;
    int stride = gridDim.x * blockDim.x;
    for (int e = i0; e < nnz; e += stride) {
        int r = rows[e], c = cols[e];
        float e1 = expf(L1[e] - fdecode(mx1[r]));
        float e2 = expf(L2[e] - fdecode(mx2[c]));
        out[e] = e1;
        out[nnz + e] = e2;
        atomicAdd(s1 + r, e1);
        atomicAdd(s2 + c, e2);
    }
}

__global__ void k_div(const int* __restrict__ rows, const int* __restrict__ cols,
                      const float* __restrict__ s1, const float* __restrict__ s2,
                      float* __restrict__ out, int nnz) {
    int i0 = blockIdx.x * blockDim.x + threadIdx.x;
    int stride = gridDim.x * blockDim.x;
    for (int e = i0; e < nnz; e += stride) {
        out[e] = out[e] / s1[rows[e]];
        out[nnz + e] = out[nnz + e] / s2[cols[e]];
    }
}

extern "C" void kernel_launch(void* const* d_in, const int* in_sizes, int n_in,
                              void* d_out, int out_size, void* d_ws, size_t ws_size,
                              hipStream_t stream) {
    const float* Xu  = (const float*)d_in[0];
    const float* Xi  = (const float*)d_in[1];
    const float* Wq  = (const float*)d_in[2];
    const float* bq  = (const float*)d_in[3];
    const float* Wk  = (const float*)d_in[4];
    const float* bk  = (const float*)d_in[5];
    const float* adj = (const float*)d_in[6];
    const float* gu1 = (const float*)d_in[7];
    const float* gu2 = (const float*)d_in[8];
    const int* rows  = (const int*)d_in[9];
    const int* cols  = (const int*)d_in[10];
    float* out = (float*)d_out;

    const int U   = in_sizes[0] / EMB;
    const int I   = in_sizes[1] / EMB;
    const int nnz = in_sizes[6];
    const int NB  = NRB * I;
    const int numB1 = (NB + 255) / 256;

    char* w = (char*)d_ws;
    size_t off_b = 0;
    auto alloc = [&](size_t elems) { char* p = w + off_b; off_b += elems * 4; return p; };

    float* BIGM = (float*)alloc(32768);
    float* v1   = (float*)alloc(128);
    float* v2   = (float*)alloc(128);
    float* c0   = (float*)alloc(64);
    float* t1   = (float*)alloc(U);
    float* t2   = (float*)alloc(U);
    float* u1   = (float*)alloc(I);
    float* u2   = (float*)alloc(I);
    float* CD   = (float*)alloc((size_t)I * 256);
    float* L1s  = (float*)alloc(nnz);
    float* L2s  = (float*)alloc(nnz);
    unsigned* mx1 = (unsigned*)alloc(U);
    unsigned* mx2 = (unsigned*)alloc(I);
    float* s1   = (float*)alloc(U);
    float* s2   = (float*)alloc(I);
    size_t base_need = off_b;
    // sort extras
    unsigned* cnt  = (unsigned*)alloc(NB);
    unsigned* offp = (unsigned*)alloc(NB);
    unsigned* bsum = (unsigned*)alloc((size_t)numB1 + 8);
    int* r_s    = (int*)alloc(nnz);
    int* c_s    = (int*)alloc(nnz);
    float* a_s  = (float*)alloc(nnz);
    float* g1_s = (float*)alloc(nnz);
    float* g2_s = (float*)alloc(nnz);
    int* iperm  = (int*)alloc(nnz);
    size_t sorted_need = off_b;

    if (base_need > ws_size) return;
    const bool use_sorted = (sorted_need <= ws_size);

    hipMemsetAsync(mx1, 0, (size_t)(2 * (U + I)) * 4, stream);  // mx1,mx2,s1,s2

    k_prep<<<128, 128, 0, stream>>>(Wq, Wk, bq, bk, BIGM, v1, v2, c0);
    k_cd<<<(I + 31) / 32, 256, 0, stream>>>(Xi, BIGM, CD, I);
    k_rowdot<<<(U + 7) / 8, 256, 0, stream>>>(Xu, U, v1, v2, t1, t2);
    k_rowdot<<<(I + 7) / 8, 256, 0, stream>>>(Xi, I, v2, v1, u1, u2);

    if (use_sorted) {
        hipMemsetAsync(cnt, 0, (size_t)NB * 4, stream);
        k_hist<<<2048, 256, 0, stream>>>(rows, cols, nnz, U, I, cnt);
        k_scan1<<<numB1, 256, 0, stream>>>(cnt, offp, bsum, NB);
        k_scan2<<<1, 256, 0, stream>>>(bsum, numB1);
        k_scan3<<<numB1, 256, 0, stream>>>(offp, bsum, NB);
        k_scatter<<<2048, 256, 0, stream>>>(rows, cols, adj, gu1, gu2, nnz, U, I,
                                            offp, r_s, c_s, a_s, g1_s, g2_s, iperm);
        k_edge3<<<4096, 256, 0, stream>>>(Xu, CD, t1, t2, u1, u2, c0,
                                          r_s, c_s, a_s, g1_s, g2_s, L1s, L2s,
                                          mx1, mx2, nnz);
        k_exp2<<<2048, 256, 0, stream>>>(r_s, c_s, L1s, L2s, mx1, mx2, s1, s2, nnz);
        k_out<<<2048, 256, 0, stream>>>(rows, cols, iperm, L1s, L2s, s1, s2, out, nnz);
    } else {
        k_edge1<<<4096, 256, 0, stream>>>(Xu, CD, t1, t2, u1, u2, c0, adj, gu1, gu2,
                                          rows, cols, L1s, L2s, mx1, mx2, nnz);
        k_exp<<<2048, 256, 0, stream>>>(L1s, L2s, rows, cols, mx1, mx2, s1, s2, out, nnz);
        k_div<<<2048, 256, 0, stream>>>(rows, cols, s1, s2, out, nnz);
    }
}

// Round 5
// 780.234 us; speedup vs baseline: 1.1186x; 1.1186x over previous
//
#include <hip/hip_runtime.h>
#include <hip/hip_bf16.h>

// Sparse graph-attention Gumbel mask.
//
// With M = Wq^T Wk [E,E]:
//   w_ui[e] = adj*( Xu[r]·C[c] + t1[r] + u1[c] + c0 ),  C = Xi M^T
//   w_iu[e] = adj*( Xu[r]·D[c] + t2[r] + u2[c] + c0 ),  D = Xi M
// Per-edge gather = Xu[r] (512B) + CD[c] (1KB).
//
// R5: counting-sort by (rblk, c), NRB=8. Edge kernel uses plain LINEAR
// chunks in blockIdx order (no XCD remap) with small per-block work
// (128 edges) so the resident-block temporal window spans ~1 bucket ->
// one 3.2MB Xu slice stays L2-hot on every XCD. 16 lanes/edge.
// Scatter payload packed (int2 + float4): 2 line-touches per edge.

#define EMB 128
#define TAUINV 2.0f
#define NRB 8
#define EPG 8   // edges per 16-lane group; EPB = 16*EPG = 128

__device__ __forceinline__ unsigned fkey(float f) {
    unsigned u = __float_as_uint(f);
    return (u & 0x80000000u) ? ~u : (u | 0x80000000u);
}
__device__ __forceinline__ float fdecode(unsigned u) {
    return __uint_as_float((u & 0x80000000u) ? (u ^ 0x80000000u) : ~u);
}

// ---- BIGM[k][j] (j<128: M[j][k]; j>=128: M[k][j-128]), v1, v2, c0
__global__ void k_prep(const float* __restrict__ Wq, const float* __restrict__ Wk,
                       const float* __restrict__ bq, const float* __restrict__ bk,
                       float* __restrict__ BIGM, float* __restrict__ v1,
                       float* __restrict__ v2, float* __restrict__ c0) {
    int e1 = blockIdx.x, e2 = threadIdx.x;
    float acc = 0.f;
    for (int a = 0; a < EMB; ++a) acc += Wq[a * EMB + e1] * Wk[a * EMB + e2];
    BIGM[e2 * 256 + e1] = acc;
    BIGM[e1 * 256 + 128 + e2] = acc;
    if (e2 == 0) { float s = 0.f; for (int a = 0; a < EMB; ++a) s += Wq[a * EMB + e1] * bk[a]; v1[e1] = s; }
    if (e2 == 1) { float s = 0.f; for (int a = 0; a < EMB; ++a) s += Wk[a * EMB + e1] * bq[a]; v2[e1] = s; }
    if (e1 == 0 && e2 == 2) { float s = 0.f; for (int a = 0; a < EMB; ++a) s += bq[a] * bk[a]; *c0 = s; }
}

// ---- CD[m][j] = sum_k Xi[m][k] * BIGM[k][j]
__global__ __launch_bounds__(256) void k_cd(const float* __restrict__ Xi,
                                            const float* __restrict__ BIGM,
                                            float* __restrict__ CD, int nItems) {
    __shared__ float Xs[32][EMB];
    __shared__ float Ms[32][256];
    const int t = threadIdx.x;
    const int m0 = blockIdx.x * 32;

    const float4* Xi4 = (const float4*)Xi;
    float4* Xs4 = (float4*)Xs;
    for (int idx = t; idx < 32 * 32; idx += 256) {
        int r = idx >> 5, c = idx & 31;
        int row = m0 + r;
        Xs4[idx] = (row < nItems) ? Xi4[(size_t)row * 32 + c]
                                  : make_float4(0.f, 0.f, 0.f, 0.f);
    }

    const int tc = t & 63;
    const int tr = t >> 6;
    float4 acc[8] = {};

    const float4* BG4 = (const float4*)BIGM;
    float4* Ms4 = (float4*)Ms;
    for (int kc = 0; kc < EMB; kc += 32) {
        __syncthreads();
        for (int idx = t; idx < 32 * 64; idx += 256)
            Ms4[idx] = BG4[(size_t)(kc + (idx >> 6)) * 64 + (idx & 63)];
        __syncthreads();
#pragma unroll
        for (int kk = 0; kk < 32; ++kk) {
            float4 w = Ms4[kk * 64 + tc];
#pragma unroll
            for (int i = 0; i < 8; ++i) {
                float x = Xs[tr * 8 + i][kc + kk];
                acc[i].x += x * w.x; acc[i].y += x * w.y;
                acc[i].z += x * w.z; acc[i].w += x * w.w;
            }
        }
    }
#pragma unroll
    for (int i = 0; i < 8; ++i) {
        int row = m0 + tr * 8 + i;
        if (row < nItems)
            ((float4*)(CD + (size_t)row * 256))[tc] = acc[i];
    }
}

// ---- o1[g] = X[g]·a, o2[g] = X[g]·b
__global__ void k_rowdot(const float* __restrict__ X, int n,
                         const float* __restrict__ a, const float* __restrict__ b,
                         float* __restrict__ o1, float* __restrict__ o2) {
    int g = blockIdx.x * 8 + (threadIdx.x >> 5);
    int l = threadIdx.x & 31;
    if (g >= n) return;
    float4 x = ((const float4*)(X + (size_t)g * EMB))[l];
    float4 av = ((const float4*)a)[l];
    float4 bv = ((const float4*)b)[l];
    float p1 = x.x * av.x + x.y * av.y + x.z * av.z + x.w * av.w;
    float p2 = x.x * bv.x + x.y * bv.y + x.z * bv.z + x.w * bv.w;
    for (int off = 16; off; off >>= 1) { p1 += __shfl_xor(p1, off); p2 += __shfl_xor(p2, off); }
    if (l == 0) { o1[g] = p1; o2[g] = p2; }
}

// ================= sort machinery =================
__global__ void k_hist(const int* __restrict__ rows, const int* __restrict__ cols,
                       int nnz, int U, int I, unsigned* __restrict__ cnt) {
    int i = blockIdx.x * blockDim.x + threadIdx.x, st = gridDim.x * blockDim.x;
    for (int e = i; e < nnz; e += st) {
        int rb = (int)(((long long)rows[e] * NRB) / U);
        atomicAdd(&cnt[rb * I + cols[e]], 1u);
    }
}

__global__ void k_scan1(const unsigned* __restrict__ cnt, unsigned* __restrict__ off,
                        unsigned* __restrict__ bsum, int n) {
    __shared__ unsigned sh[256];
    int i = blockIdx.x * 256 + threadIdx.x;
    unsigned v = (i < n) ? cnt[i] : 0u;
    sh[threadIdx.x] = v; __syncthreads();
    for (int d = 1; d < 256; d <<= 1) {
        unsigned t = (threadIdx.x >= d) ? sh[threadIdx.x - d] : 0u; __syncthreads();
        sh[threadIdx.x] += t; __syncthreads();
    }
    if (i < n) off[i] = sh[threadIdx.x] - v;
    if (threadIdx.x == 255) bsum[blockIdx.x] = sh[255];
}

__global__ void k_scan2(unsigned* __restrict__ bsum, int nb) {
    __shared__ unsigned sh[256];
    __shared__ unsigned carry;
    if (threadIdx.x == 0) carry = 0u;
    __syncthreads();
    for (int base = 0; base < nb; base += 256) {
        int i = base + threadIdx.x;
        unsigned v = (i < nb) ? bsum[i] : 0u;
        sh[threadIdx.x] = v; __syncthreads();
        for (int d = 1; d < 256; d <<= 1) {
            unsigned t = (threadIdx.x >= d) ? sh[threadIdx.x - d] : 0u; __syncthreads();
            sh[threadIdx.x] += t; __syncthreads();
        }
        unsigned c = carry;
        if (i < nb) bsum[i] = c + sh[threadIdx.x] - v;
        __syncthreads();
        if (threadIdx.x == 0) carry = c + sh[255];
        __syncthreads();
    }
}

__global__ void k_scan3(unsigned* __restrict__ off, const unsigned* __restrict__ bsum, int n) {
    int i = blockIdx.x * 256 + threadIdx.x;
    if (i < n) off[i] += bsum[blockIdx.x];
}

__global__ void k_scatter(const int* __restrict__ rows, const int* __restrict__ cols,
                          const float* __restrict__ adj, const float* __restrict__ gu1,
                          const float* __restrict__ gu2, int nnz, int U, int I,
                          unsigned* __restrict__ off, int2* __restrict__ ec_s,
                          float4* __restrict__ fg_s, int* __restrict__ iperm) {
    int i = blockIdx.x * blockDim.x + threadIdx.x, st = gridDim.x * blockDim.x;
    for (int e = i; e < nnz; e += st) {
        int r = rows[e], c = cols[e];
        int rb = (int)(((long long)r * NRB) / U);
        unsigned pos = atomicAdd(&off[rb * I + c], 1u);
        ec_s[pos] = make_int2(r, c);
        fg_s[pos] = make_float4(adj[e], gu1[e], gu2[e], 0.f);
        iperm[e] = (int)pos;
    }
}

// ---- sorted edge kernel: linear chunks (blockIdx order == sorted order),
// 16 lanes per edge, small per-block work to keep the temporal window narrow.
__global__ __launch_bounds__(256) void k_edge4(
    const float* __restrict__ Xu, const float* __restrict__ CD,
    const float* __restrict__ t1, const float* __restrict__ t2,
    const float* __restrict__ u1, const float* __restrict__ u2,
    const float* __restrict__ c0p,
    const int2* __restrict__ ec_s, const float4* __restrict__ fg_s,
    float* __restrict__ L1s, float* __restrict__ L2s,
    unsigned* __restrict__ mx1, unsigned* __restrict__ mx2, int nnz) {
    const int g = threadIdx.x >> 4, l = threadIdx.x & 15;
    size_t j0 = ((size_t)blockIdx.x * 16 + g) * EPG;
    size_t j1 = j0 + EPG; if (j1 > (size_t)nnz) j1 = (size_t)nnz;
    const float c0 = *c0p;
    for (size_t j = j0; j < j1; ++j) {
        int2 ec = ec_s[j];
        int r = ec.x, c = ec.y;
        const float4* xu = (const float4*)(Xu + (size_t)r * EMB);
        const float4* cd = (const float4*)(CD + (size_t)c * 256);
        float4 x0 = xu[l], x1 = xu[l + 16];
        float4 cv0 = cd[l], cv1 = cd[l + 16];
        float4 dv0 = cd[l + 32], dv1 = cd[l + 48];
        float p1 = x0.x * cv0.x + x0.y * cv0.y + x0.z * cv0.z + x0.w * cv0.w
                 + x1.x * cv1.x + x1.y * cv1.y + x1.z * cv1.z + x1.w * cv1.w;
        float p2 = x0.x * dv0.x + x0.y * dv0.y + x0.z * dv0.z + x0.w * dv0.w
                 + x1.x * dv1.x + x1.y * dv1.y + x1.z * dv1.z + x1.w * dv1.w;
#pragma unroll
        for (int off = 1; off < 16; off <<= 1) {
            p1 += __shfl_xor(p1, off);
            p2 += __shfl_xor(p2, off);
        }
        if (l < 2) {
            float4 fg = fg_s[j];
            float p  = (l == 0) ? p1 : p2;
            float gu = (l == 0) ? fg.y : fg.z;
            float tt = (l == 0) ? t1[r] : t2[r];
            float uu = (l == 0) ? u1[c] : u2[c];
            float gg = logf(-logf(gu));   // logf: u near 1 needs relative accuracy
            float lg = (fg.x * (p + tt + uu + c0) - gg) * TAUINV;
            if (l == 0) { L1s[j] = lg; atomicMax(mx1 + r, fkey(lg)); }
            else        { L2s[j] = lg; atomicMax(mx2 + c, fkey(lg)); }
        }
    }
}

// ---- exp + segment sums (sorted order, per-edge atomics)
__global__ void k_exp2(const int2* __restrict__ ec_s,
                       float* __restrict__ L1s, float* __restrict__ L2s,
                       const unsigned* __restrict__ mx1, const unsigned* __restrict__ mx2,
                       float* __restrict__ s1, float* __restrict__ s2, int nnz) {
    int i = blockIdx.x * blockDim.x + threadIdx.x, st = gridDim.x * blockDim.x;
    for (int j = i; j < nnz; j += st) {
        int2 ec = ec_s[j];
        float e1 = expf(L1s[j] - fdecode(mx1[ec.x]));
        float e2 = expf(L2s[j] - fdecode(mx2[ec.y]));
        L1s[j] = e1; L2s[j] = e2;
        atomicAdd(s1 + ec.x, e1);
        atomicAdd(s2 + ec.y, e2);
    }
}

// ---- un-permute + normalize
__global__ void k_out(const int* __restrict__ rows, const int* __restrict__ cols,
                      const int* __restrict__ iperm, const float* __restrict__ L1s,
                      const float* __restrict__ L2s, const float* __restrict__ s1,
                      const float* __restrict__ s2, float* __restrict__ out, int nnz) {
    int i = blockIdx.x * blockDim.x + threadIdx.x, st = gridDim.x * blockDim.x;
    for (int e = i; e < nnz; e += st) {
        int p = iperm[e];
        out[e] = L1s[p] / s1[rows[e]];
        out[nnz + e] = L2s[p] / s2[cols[e]];
    }
}

// ================= fallback (unsorted) path =================
__global__ __launch_bounds__(256) void k_edge1(
    const float* __restrict__ Xu, const float* __restrict__ CD,
    const float* __restrict__ t1, const float* __restrict__ t2,
    const float* __restrict__ u1, const float* __restrict__ u2,
    const float* __restrict__ c0p, const float* __restrict__ adj,
    const float* __restrict__ gu1, const float* __restrict__ gu2,
    const int* __restrict__ rows, const int* __restrict__ cols,
    float* __restrict__ L1, float* __restrict__ L2,
    unsigned* __restrict__ mx1, unsigned* __restrict__ mx2, int nnz) {
    const int gid = blockIdx.x * 8 + (threadIdx.x >> 5);
    const int l = threadIdx.x & 31;
    const int stride = gridDim.x * 8;
    const float c0 = *c0p;
    for (int e = gid; e < nnz; e += stride) {
        int r = rows[e], c = cols[e];
        float4 xu = ((const float4*)(Xu + (size_t)r * EMB))[l];
        const float4* cd = (const float4*)(CD + (size_t)c * 256);
        float4 cv = cd[l];
        float4 dv = cd[32 + l];
        float p1 = xu.x * cv.x + xu.y * cv.y + xu.z * cv.z + xu.w * cv.w;
        float p2 = xu.x * dv.x + xu.y * dv.y + xu.z * dv.z + xu.w * dv.w;
        for (int off = 16; off; off >>= 1) { p1 += __shfl_xor(p1, off); p2 += __shfl_xor(p2, off); }
        if (l < 2) {
            float p = (l == 0) ? p1 : p2;
            float tt = (l == 0) ? t1[r] : t2[r];
            float uu = (l == 0) ? u1[c] : u2[c];
            float g = logf(-logf(((l == 0) ? gu1 : gu2)[e]));
            float w = adj[e] * (p + tt + uu + c0);
            float lg = (w - g) * TAUINV;
            if (l == 0) { L1[e] = lg; atomicMax(mx1 + r, fkey(lg)); }
            else        { L2[e] = lg; atomicMax(mx2 + c, fkey(lg)); }
        }
    }
}

__global__ void k_exp(const float* __restrict__ L1, const float* __restrict__ L2,
                      const int* __restrict__ rows, const int* __restrict__ cols,
                      const unsigned* __restrict__ mx1, const unsigned* __restrict__ mx2,
                      float* __restrict__ s1, float* __restrict__ s2,
                      float* __restrict__ out, int nnz) {
    int i0 = blockIdx.x * blockDim.x + threadIdx.x;
    int stride = gridDim.x * blockDim.x;
    for (int e = i0; e < nnz; e += stride) {
        int r = rows[e], c = cols[e];
        float e1 = expf(L1[e] - fdecode(mx1[r]));
        float e2 = expf(L2[e] - fdecode(mx2[c]));
        out[e] = e1;
        out[nnz + e] = e2;
        atomicAdd(s1 + r, e1);
        atomicAdd(s2 + c, e2);
    }
}

__global__ void k_div(const int* __restrict__ rows, const int* __restrict__ cols,
                      const float* __restrict__ s1, const float* __restrict__ s2,
                      float* __restrict__ out, int nnz) {
    int i0 = blockIdx.x * blockDim.x + threadIdx.x;
    int stride = gridDim.x * blockDim.x;
    for (int e = i0; e < nnz; e += stride) {
        out[e] = out[e] / s1[rows[e]];
        out[nnz + e] = out[nnz + e] / s2[cols[e]];
    }
}

extern "C" void kernel_launch(void* const* d_in, const int* in_sizes, int n_in,
                              void* d_out, int out_size, void* d_ws, size_t ws_size,
                              hipStream_t stream) {
    const float* Xu  = (const float*)d_in[0];
    const float* Xi  = (const float*)d_in[1];
    const float* Wq  = (const float*)d_in[2];
    const float* bq  = (const float*)d_in[3];
    const float* Wk  = (const float*)d_in[4];
    const float* bk  = (const float*)d_in[5];
    const float* adj = (const float*)d_in[6];
    const float* gu1 = (const float*)d_in[7];
    const float* gu2 = (const float*)d_in[8];
    const int* rows  = (const int*)d_in[9];
    const int* cols  = (const int*)d_in[10];
    float* out = (float*)d_out;

    const int U   = in_sizes[0] / EMB;
    const int I   = in_sizes[1] / EMB;
    const int nnz = in_sizes[6];
    const int NB  = NRB * I;
    const int numB1 = (NB + 255) / 256;

    char* w = (char*)d_ws;
    size_t off_b = 0;
    auto alloc = [&](size_t bytes) {
        char* p = w + off_b;
        off_b += (bytes + 15) & ~(size_t)15;   // 16B-align every block
        return p;
    };

    float* BIGM = (float*)alloc(32768 * 4);
    float* v1   = (float*)alloc(128 * 4);
    float* v2   = (float*)alloc(128 * 4);
    float* c0   = (float*)alloc(64 * 4);
    float* t1   = (float*)alloc((size_t)U * 4);
    float* t2   = (float*)alloc((size_t)U * 4);
    float* u1   = (float*)alloc((size_t)I * 4);
    float* u2   = (float*)alloc((size_t)I * 4);
    float* CD   = (float*)alloc((size_t)I * 256 * 4);
    float* L1s  = (float*)alloc((size_t)nnz * 4);
    float* L2s  = (float*)alloc((size_t)nnz * 4);
    unsigned* mx1 = (unsigned*)alloc((size_t)U * 4);
    unsigned* mx2 = (unsigned*)alloc((size_t)I * 4);
    float* s1   = (float*)alloc((size_t)U * 4);
    float* s2   = (float*)alloc((size_t)I * 4);
    size_t base_need = off_b;
    // sort extras
    unsigned* cnt  = (unsigned*)alloc((size_t)NB * 4);
    unsigned* offp = (unsigned*)alloc((size_t)NB * 4);
    unsigned* bsum = (unsigned*)alloc(((size_t)numB1 + 8) * 4);
    int2*   ec_s  = (int2*)alloc((size_t)nnz * 8);
    float4* fg_s  = (float4*)alloc((size_t)nnz * 16);
    int*    iperm = (int*)alloc((size_t)nnz * 4);
    size_t sorted_need = off_b;

    if (base_need > ws_size) return;
    const bool use_sorted = (sorted_need <= ws_size);

    hipMemsetAsync(mx1, 0, (size_t)(2 * (U + I)) * 4, stream);  // mx1,mx2,s1,s2

    k_prep<<<128, 128, 0, stream>>>(Wq, Wk, bq, bk, BIGM, v1, v2, c0);
    k_cd<<<(I + 31) / 32, 256, 0, stream>>>(Xi, BIGM, CD, I);
    k_rowdot<<<(U + 7) / 8, 256, 0, stream>>>(Xu, U, v1, v2, t1, t2);
    k_rowdot<<<(I + 7) / 8, 256, 0, stream>>>(Xi, I, v2, v1, u1, u2);

    if (use_sorted) {
        hipMemsetAsync(cnt, 0, (size_t)NB * 4, stream);
        k_hist<<<2048, 256, 0, stream>>>(rows, cols, nnz, U, I, cnt);
        k_scan1<<<numB1, 256, 0, stream>>>(cnt, offp, bsum, NB);
        k_scan2<<<1, 256, 0, stream>>>(bsum, numB1);
        k_scan3<<<numB1, 256, 0, stream>>>(offp, bsum, NB);
        k_scatter<<<2048, 256, 0, stream>>>(rows, cols, adj, gu1, gu2, nnz, U, I,
                                            offp, ec_s, fg_s, iperm);
        const int EPB = 16 * EPG;
        k_edge4<<<(nnz + EPB - 1) / EPB, 256, 0, stream>>>(
            Xu, CD, t1, t2, u1, u2, c0, ec_s, fg_s, L1s, L2s, mx1, mx2, nnz);
        k_exp2<<<2048, 256, 0, stream>>>(ec_s, L1s, L2s, mx1, mx2, s1, s2, nnz);
        k_out<<<2048, 256, 0, stream>>>(rows, cols, iperm, L1s, L2s, s1, s2, out, nnz);
    } else {
        k_edge1<<<4096, 256, 0, stream>>>(Xu, CD, t1, t2, u1, u2, c0, adj, gu1, gu2,
                                          rows, cols, L1s, L2s, mx1, mx2, nnz);
        k_exp<<<2048, 256, 0, stream>>>(L1s, L2s, rows, cols, mx1, mx2, s1, s2, out, nnz);
        k_div<<<2048, 256, 0, stream>>>(rows, cols, s1, s2, out, nnz);
    }
}